// Round 7
// baseline (189.287 us; speedup 1.0000x reference)
//
#include <hip/hip_runtime.h>
#include <hip/hip_fp16.h>

#define NG    32
#define DG    64
#define NPL   64
#define CPD2  16               // sort granularity (fine cells)
#define NC2   4096             // 16^3 sort bins
#define NCELL 512              // gather cells (8^3)
#define HPAD  4                // ints per padded counter (16B)
#define BS    512
#define TV    4096             // 16^3 voxels per tile
#define HS    68               // mlp sH row stride (f16) — bank-conflict pad

typedef _Float16 half8 __attribute__((ext_vector_type(8)));
typedef float    floatx4 __attribute__((ext_vector_type(4)));

// ---------------------------------------------------------------------------
// Pack: [G][2][64][64][64] f32 -> [G][64][64][64] half2  (vectorized x4)
// ---------------------------------------------------------------------------
__global__ void pack_grids_kernel(const float* __restrict__ fg,
                                  uint4* __restrict__ pg, int total4) {
    int idx = blockIdx.x * blockDim.x + threadIdx.x;
    if (idx >= total4) return;
    int g  = idx >> 16;
    int v4 = (idx & 65535) << 2;
    const float* base = fg + ((size_t)g << 19);
    float4 a = *(const float4*)(base + v4);
    float4 b = *(const float4*)(base + (1 << 18) + v4);
    uint4 o;
    __half2 h;
    h = __floats2half2_rn(a.x, b.x); o.x = *(unsigned*)&h;
    h = __floats2half2_rn(a.y, b.y); o.y = *(unsigned*)&h;
    h = __floats2half2_rn(a.z, b.z); o.z = *(unsigned*)&h;
    h = __floats2half2_rn(a.w, b.w); o.w = *(unsigned*)&h;
    pg[idx] = o;
}

// ---------------------------------------------------------------------------
// Morton helpers. Fine code (4 bits/dim): low 3 bits = octant within the
// coarse 8^3 cell, so fine codes [c*8, c*8+8) are coarse cell c's children.
// ---------------------------------------------------------------------------
__device__ __forceinline__ int morton16(int cx, int cy, int cz) {
    int m = 0;
    #pragma unroll
    for (int b = 0; b < 4; ++b)
        m |= (((cx >> b) & 1) << (3 * b))
           | (((cy >> b) & 1) << (3 * b + 1))
           | (((cz >> b) & 1) << (3 * b + 2));
    return m;
}
__device__ __forceinline__ int cell_of(float px, float py, float pz) {
    int cx = min(max((int)((px + 1.0f) * (0.5f * CPD2)), 0), CPD2 - 1);
    int cy = min(max((int)((py + 1.0f) * (0.5f * CPD2)), 0), CPD2 - 1);
    int cz = min(max((int)((pz + 1.0f) * (0.5f * CPD2)), 0), CPD2 - 1);
    return morton16(cx, cy, cz);
}

__global__ __launch_bounds__(BS)
void hist_kernel(const float* __restrict__ x, int N, int* __restrict__ ghist) {
    __shared__ int lh[NC2];
    for (int i = threadIdx.x; i < NC2; i += BS) lh[i] = 0;
    __syncthreads();
    int n = blockIdx.x * BS + threadIdx.x;
    if (n < N) atomicAdd(&lh[cell_of(x[3*n], x[3*n+1], x[3*n+2])], 1);
    __syncthreads();
    for (int i = threadIdx.x; i < NC2; i += BS) {
        int c = lh[i];
        if (c) atomicAdd(&ghist[i * HPAD], c);
    }
}

__global__ __launch_bounds__(1024)
void scan_kernel(const int* __restrict__ ghist, int* __restrict__ gcursor,
                 int* __restrict__ cellstart) {
    __shared__ int tsum[1024];
    int t = threadIdx.x;
    int v0 = ghist[(t * 4 + 0) * HPAD];
    int v1 = ghist[(t * 4 + 1) * HPAD];
    int v2 = ghist[(t * 4 + 2) * HPAD];
    int v3 = ghist[(t * 4 + 3) * HPAD];
    tsum[t] = v0 + v1 + v2 + v3;
    __syncthreads();
    #pragma unroll
    for (int off = 1; off < 1024; off <<= 1) {
        int u = (t >= off) ? tsum[t - off] : 0;
        __syncthreads();
        tsum[t] += u;
        __syncthreads();
    }
    int base = (t == 0) ? 0 : tsum[t - 1];
    gcursor[(t*4+0)*HPAD] = base; cellstart[t*4+0] = base; base += v0;
    gcursor[(t*4+1)*HPAD] = base; cellstart[t*4+1] = base; base += v1;
    gcursor[(t*4+2)*HPAD] = base; cellstart[t*4+2] = base; base += v2;
    gcursor[(t*4+3)*HPAD] = base; cellstart[t*4+3] = base;
    if (t == 1023) cellstart[NC2] = tsum[1023];
}

__global__ __launch_bounds__(BS)
void scatter_kernel(const float* __restrict__ x, int N,
                    int* __restrict__ gcursor, float4* __restrict__ sorted,
                    int* __restrict__ nidx) {
    __shared__ int cnt[NC2];
    __shared__ int base[NC2];
    int tid = threadIdx.x;
    for (int i = tid; i < NC2; i += BS) cnt[i] = 0;
    __syncthreads();
    int n = blockIdx.x * BS + tid;
    float px = 0.f, py = 0.f, pz = 0.f;
    int c = 0, r = 0;
    bool act = (n < N);
    if (act) {
        px = x[3*n]; py = x[3*n+1]; pz = x[3*n+2];
        c = cell_of(px, py, pz);
        r = atomicAdd(&cnt[c], 1);
    }
    __syncthreads();
    for (int i = tid; i < NC2; i += BS) {
        int cc = cnt[i];
        base[i] = cc ? atomicAdd(&gcursor[i * HPAD], cc) : 0;
    }
    __syncthreads();
    if (act) {
        int pos = base[c] + r;
        sorted[pos] = make_float4(px, py, pz, 0.0f);
        nidx[pos]   = n;
    }
}

// ---------------------------------------------------------------------------
__device__ __forceinline__ float2 h2_to_f2(unsigned u) {
    __half2 h = *reinterpret_cast<__half2*>(&u);
    return __half22float2(h);
}

template<bool FAST>
__device__ __forceinline__ unsigned sample_tile(
    const unsigned* __restrict__ tl,
    float px, float py, float pz,
    float A0, float A1, float A2, float B0, float B1, float B2,
    int ox, int oy, int oz)
{
    float fx = fmaf(px, A0, B0);
    float fy = fmaf(py, A1, B1);
    float fz = fmaf(pz, A2, B2);
    float flx = floorf(fx), fly = floorf(fy), flz = floorf(fz);
    int x0 = (int)flx, y0 = (int)fly, z0 = (int)flz;
    float wx = fx - flx, wy = fy - fly, wz = fz - flz;

    float wxa0, wxa1, wya0, wya1, wza0, wza1;
    if (FAST) {   // whole cell strictly interior: no boundary masks needed
        wxa0 = 1.0f - wx; wxa1 = wx;
        wya0 = 1.0f - wy; wya1 = wy;
        wza0 = 1.0f - wz; wza1 = wz;
    } else {
        wxa0 = (x0 >= 0  && x0     < DG) ? (1.0f - wx) : 0.0f;
        wxa1 = (x0 >= -1 && x0 + 1 < DG) ? wx          : 0.0f;
        wya0 = (y0 >= 0  && y0     < DG) ? (1.0f - wy) : 0.0f;
        wya1 = (y0 >= -1 && y0 + 1 < DG) ? wy          : 0.0f;
        wza0 = (z0 >= 0  && z0     < DG) ? (1.0f - wz) : 0.0f;
        wza1 = (z0 >= -1 && z0 + 1 < DG) ? wz          : 0.0f;
    }
    int ix0 = min(max(x0     - ox, 0), 15);
    int ix1 = min(max(x0 + 1 - ox, 0), 15);
    int iy0 = (min(max(y0     - oy, 0), 15)) << 4;
    int iy1 = (min(max(y0 + 1 - oy, 0), 15)) << 4;
    int iz0 = (min(max(z0     - oz, 0), 15)) << 8;
    int iz1 = (min(max(z0 + 1 - oz, 0), 15)) << 8;

    float w00 = wya0 * wza0, w10 = wya1 * wza0;
    float w01 = wya0 * wza1, w11 = wya1 * wza1;

    float c0 = 0.0f, c1 = 0.0f;
    float2 v;
    v = h2_to_f2(tl[iz0+iy0+ix0]); c0 = fmaf(wxa0*w00, v.x, c0); c1 = fmaf(wxa0*w00, v.y, c1);
    v = h2_to_f2(tl[iz0+iy0+ix1]); c0 = fmaf(wxa1*w00, v.x, c0); c1 = fmaf(wxa1*w00, v.y, c1);
    v = h2_to_f2(tl[iz0+iy1+ix0]); c0 = fmaf(wxa0*w10, v.x, c0); c1 = fmaf(wxa0*w10, v.y, c1);
    v = h2_to_f2(tl[iz0+iy1+ix1]); c0 = fmaf(wxa1*w10, v.x, c0); c1 = fmaf(wxa1*w10, v.y, c1);
    v = h2_to_f2(tl[iz1+iy0+ix0]); c0 = fmaf(wxa0*w01, v.x, c0); c1 = fmaf(wxa0*w01, v.y, c1);
    v = h2_to_f2(tl[iz1+iy0+ix1]); c0 = fmaf(wxa1*w01, v.x, c0); c1 = fmaf(wxa1*w01, v.y, c1);
    v = h2_to_f2(tl[iz1+iy1+ix0]); c0 = fmaf(wxa0*w11, v.x, c0); c1 = fmaf(wxa0*w11, v.y, c1);
    v = h2_to_f2(tl[iz1+iy1+ix1]); c0 = fmaf(wxa1*w11, v.x, c0); c1 = fmaf(wxa1*w11, v.y, c1);

    __half2 hv = __floats2half2_rn(c0, c1);
    return *reinterpret_cast<unsigned*>(&hv);
}

// ---------------------------------------------------------------------------
// Gather: 1024 blocks = 2 per 8^3 cell (contiguous half-split, same XCD).
// Per-(cell,grid) classification: 0=skip (zero contribution), 1=fast
// (strictly interior), 2=slow. Skipped grids are neither staged nor sampled.
// ---------------------------------------------------------------------------
__global__ __launch_bounds__(BS)
void gather_kernel(const float4* __restrict__ sorted,
                   const int*   __restrict__ cs16,
                   const float* __restrict__ scales,
                   const float* __restrict__ trans,
                   const unsigned* __restrict__ pg,
                   int4* __restrict__ featbuf, int N)
{
    __shared__ float    sA[NG * 3];
    __shared__ float    sB[NG * 3];
    __shared__ int      sO[NG * 3];
    __shared__ int      sCls[NG];
    __shared__ int      sList[NG + 1];
    __shared__ unsigned tile[2][TV];      // 32 KB

    const int tid  = threadIdx.x;
    const int bid  = blockIdx.x;
    const int half = bid >> 9;                       // same XCD as partner
    const int cell = bid & 511;
    const int c    = ((cell & 7) << 6) + (cell >> 3); // XCD-chunked swizzle

    int s0c = cs16[c * 8];
    int ec  = cs16[c * 8 + 8];
    int cnt = ec - s0c;
    int hsz = (cnt + 1) >> 1;
    int start = s0c + half * hsz;
    int end   = min(ec, start + hsz);
    if (start >= end) return;            // uniform exit before any barrier

    int cx = (c & 1)        | (((c >> 3) & 1) << 1) | (((c >> 6) & 1) << 2);
    int cy = ((c >> 1) & 1) | (((c >> 4) & 1) << 1) | (((c >> 7) & 1) << 2);
    int cz = ((c >> 2) & 1) | (((c >> 5) & 1) << 1) | (((c >> 8) & 1) << 2);

    if (tid < NG * 3) {
        const float k = (1.0f / 1.48f) * 31.5f;
        float A  = scales[tid] * k;
        float Bv = trans[tid] * k + 31.5f;
        sA[tid] = A; sB[tid] = Bv;
        int d  = tid % 3;
        int cc = (d == 0) ? cx : ((d == 1) ? cy : cz);
        int o  = (int)floorf(fmaf((float)cc * 0.25f - 1.0f, A, Bv));
        sO[tid] = min(max(o, 0), 48);
    }
    __syncthreads();
    if (tid < NG) {
        bool skip = false, fast = true;
        #pragma unroll
        for (int d = 0; d < 3; ++d) {
            float A = sA[3 * tid + d], B = sB[3 * tid + d];
            int  cc = (d == 0) ? cx : ((d == 1) ? cy : cz);
            float lo = fmaf((float)cc, 0.25f, -1.0f) - 1e-4f;
            float hi = lo + 0.25f + 2e-4f;
            float fmn = fmaf(lo, A, B);   // A > 0 always (scales > 0)
            float fmx = fmaf(hi, A, B);
            skip = skip || (fmx <= -1.0f) || (fmn >= 64.0f);
            fast = fast && (fmn >= 0.0f) && (fmx <= 63.0f);
        }
        sCls[tid] = skip ? 0 : (fast ? 1 : 2);
    }
    __syncthreads();
    if (tid == 0) {
        int n2 = 0;
        for (int g = 0; g < NG; ++g)
            if (sCls[g]) sList[n2++] = g;
        sList[NG] = n2;
    }
    __syncthreads();
    const int nAct = sList[NG];

    // per-thread points (2 slots; hsz <= ~620 << 1024 capacity)
    int  ip0 = start + tid,        ip1 = start + BS + tid;
    bool act0 = (ip0 < end),       act1 = (ip1 < end);
    float px0 = 0.f, py0 = 0.f, pz0 = 0.f;
    float px1 = 0.f, py1 = 0.f, pz1 = 0.f;
    if (act0) { float4 q = sorted[ip0]; px0 = q.x; py0 = q.y; pz0 = q.z; }
    if (act1) { float4 q = sorted[ip1]; px1 = q.x; py1 = q.y; pz1 = q.z; }

    // prologue: stage first active grid into buf 0
    if (nAct > 0) {
        int g0 = sList[0];
        int ox = sO[3*g0], oy = sO[3*g0+1], oz = sO[3*g0+2];
        const unsigned* gb = pg + ((size_t)g0 << 18);
        #pragma unroll
        for (int jj = 0; jj < 8; ++jj) {
            int v = tid + (jj << 9);
            tile[0][v] = gb[((oz + (v >> 8)) << 12) + ((oy + ((v >> 4) & 15)) << 6)
                            + ox + (v & 15)];
        }
    }
    __syncthreads();

    unsigned fp0[4], fp1[4];
    unsigned r[8];
    int j = 0;

    #pragma unroll 1
    for (int w = 0; w < 8; ++w) {
        #pragma unroll
        for (int q = 0; q < 4; ++q) {
            int g   = 4 * w + q;
            int cls = sCls[g];                 // block-uniform
            if (cls == 0) { fp0[q] = 0u; fp1[q] = 0u; continue; }

            const unsigned* tl = &tile[j & 1][0];
            bool more = (j + 1 < nAct);
            if (more) {                        // issue next tile's loads
                int gn = sList[j + 1];
                int ox = sO[3*gn], oy = sO[3*gn+1], oz = sO[3*gn+2];
                const unsigned* gb = pg + ((size_t)gn << 18);
                #pragma unroll
                for (int jj = 0; jj < 8; ++jj) {
                    int v = tid + (jj << 9);
                    r[jj] = gb[((oz + (v >> 8)) << 12) + ((oy + ((v >> 4) & 15)) << 6)
                               + ox + (v & 15)];
                }
            }

            float A0 = sA[3*g], A1 = sA[3*g+1], A2 = sA[3*g+2];
            float B0 = sB[3*g], B1 = sB[3*g+1], B2 = sB[3*g+2];
            int   ox = sO[3*g], oy = sO[3*g+1], oz = sO[3*g+2];
            if (cls == 1) {
                fp0[q] = act0 ? sample_tile<true >(tl, px0,py0,pz0, A0,A1,A2,B0,B1,B2, ox,oy,oz) : 0u;
                fp1[q] = act1 ? sample_tile<true >(tl, px1,py1,pz1, A0,A1,A2,B0,B1,B2, ox,oy,oz) : 0u;
            } else {
                fp0[q] = act0 ? sample_tile<false>(tl, px0,py0,pz0, A0,A1,A2,B0,B1,B2, ox,oy,oz) : 0u;
                fp1[q] = act1 ? sample_tile<false>(tl, px1,py1,pz1, A0,A1,A2,B0,B1,B2, ox,oy,oz) : 0u;
            }

            if (more) {                        // land staged regs into other buf
                unsigned* td = &tile[(j & 1) ^ 1][0];
                #pragma unroll
                for (int jj = 0; jj < 8; ++jj) td[tid + (jj << 9)] = r[jj];
            }
            __syncthreads();
            ++j;
        }
        const size_t plane = (size_t)w * (size_t)N;
        if (act0) featbuf[plane + ip0] =
            make_int4((int)fp0[0], (int)fp0[1], (int)fp0[2], (int)fp0[3]);
        if (act1) featbuf[plane + ip1] =
            make_int4((int)fp1[0], (int)fp1[1], (int)fp1[2], (int)fp1[3]);
    }
}

// ---------------------------------------------------------------------------
// MFMA MLP: wave = 64 points; A from featbuf planes, B = W rows (f16, LDS).
// sH row stride padded to 68 f16 to break 16-way ds_read_b128 bank aliasing.
// ---------------------------------------------------------------------------
#define MBS 256
__global__ __launch_bounds__(MBS)
void mlp_kernel(const int4* __restrict__ featbuf,
                const int* __restrict__ nidx,
                const float* __restrict__ W0, const float* __restrict__ b0,
                const float* __restrict__ W1, const float* __restrict__ b1,
                const float* __restrict__ W2, const float* __restrict__ b2,
                float* __restrict__ out, int N)
{
    __shared__ __align__(16) _Float16 sW0h[NPL * NPL];
    __shared__ __align__(16) _Float16 sW1h[NPL * NPL];
    __shared__ float sb0f[NPL], sb1f[NPL], sW2f[NPL];
    __shared__ __align__(16) _Float16 sH[4][NPL * HS];

    int tid = threadIdx.x;
    for (int i = tid; i < NPL * NPL; i += MBS) {
        sW0h[i] = (_Float16)W0[i];
        sW1h[i] = (_Float16)W1[i];
    }
    if (tid < NPL) { sb0f[tid] = b0[tid]; sb1f[tid] = b1[tid]; sW2f[tid] = W2[tid]; }
    __syncthreads();

    const int wave = tid >> 6;
    const int lane = tid & 63;
    const int l15  = lane & 15;
    const int kg   = lane >> 4;
    const long wbase = (long)blockIdx.x * MBS + wave * 64;
    if (wbase >= N) return;

    half8 B0[4][2], B1[4][2];
    float bias0[4], bias1[4], w2v[4];
    #pragma unroll
    for (int nt = 0; nt < 4; ++nt) {
        int ch = nt * 16 + l15;
        #pragma unroll
        for (int kh = 0; kh < 2; ++kh) {
            int k = kh * 32 + kg * 8;
            B0[nt][kh] = *(const half8*)&sW0h[ch * NPL + k];
            B1[nt][kh] = *(const half8*)&sW1h[ch * NPL + k];
        }
        bias0[nt] = sb0f[ch];
        bias1[nt] = sb1f[ch];
        w2v[nt]   = sW2f[ch];
    }

    _Float16* H = &sH[wave][0];

    // ---- layer 0 ----
    floatx4 acc[4][4];
    #pragma unroll
    for (int mt = 0; mt < 4; ++mt) {
        long pt = wbase + mt * 16 + l15;
        if (pt > N - 1) pt = N - 1;
        int4 t0 = featbuf[(size_t)kg * N + pt];
        int4 t1 = featbuf[(size_t)(4 + kg) * N + pt];
        half8 a0 = *reinterpret_cast<half8*>(&t0);
        half8 a1 = *reinterpret_cast<half8*>(&t1);
        #pragma unroll
        for (int nt = 0; nt < 4; ++nt) {
            floatx4 cc = {0.f, 0.f, 0.f, 0.f};
            cc = __builtin_amdgcn_mfma_f32_16x16x32_f16(a0, B0[nt][0], cc, 0, 0, 0);
            cc = __builtin_amdgcn_mfma_f32_16x16x32_f16(a1, B0[nt][1], cc, 0, 0, 0);
            acc[mt][nt] = cc;
        }
    }
    #pragma unroll
    for (int mt = 0; mt < 4; ++mt)
        #pragma unroll
        for (int nt = 0; nt < 4; ++nt) {
            int ch = nt * 16 + l15;
            #pragma unroll
            for (int r = 0; r < 4; ++r) {
                float v = fmaxf(acc[mt][nt][r] + bias0[nt], 0.0f);
                H[(mt * 16 + kg * 4 + r) * HS + ch] = (_Float16)v;
            }
        }

    // ---- layer 1 ----
    floatx4 acc2[4][4];
    #pragma unroll
    for (int mt = 0; mt < 4; ++mt) {
        const _Float16* hp = &H[(mt * 16 + l15) * HS];
        half8 a0 = *(const half8*)&hp[kg * 8];
        half8 a1 = *(const half8*)&hp[32 + kg * 8];
        #pragma unroll
        for (int nt = 0; nt < 4; ++nt) {
            floatx4 cc = {0.f, 0.f, 0.f, 0.f};
            cc = __builtin_amdgcn_mfma_f32_16x16x32_f16(a0, B1[nt][0], cc, 0, 0, 0);
            cc = __builtin_amdgcn_mfma_f32_16x16x32_f16(a1, B1[nt][1], cc, 0, 0, 0);
            acc2[mt][nt] = cc;
        }
    }

    // ---- layer 2 + 16-lane reduce ----
    float p[4][4];
    #pragma unroll
    for (int mt = 0; mt < 4; ++mt)
        #pragma unroll
        for (int r = 0; r < 4; ++r) p[mt][r] = 0.0f;
    #pragma unroll
    for (int mt = 0; mt < 4; ++mt)
        #pragma unroll
        for (int nt = 0; nt < 4; ++nt)
            #pragma unroll
            for (int r = 0; r < 4; ++r) {
                float v = fmaxf(acc2[mt][nt][r] + bias1[nt], 0.0f);
                p[mt][r] = fmaf(v, w2v[nt], p[mt][r]);
            }
    #pragma unroll
    for (int mt = 0; mt < 4; ++mt)
        #pragma unroll
        for (int r = 0; r < 4; ++r) {
            float s = p[mt][r];
            s += __shfl_xor(s, 1);
            s += __shfl_xor(s, 2);
            s += __shfl_xor(s, 4);
            s += __shfl_xor(s, 8);
            p[mt][r] = s;
        }

    float* HF = (float*)H;
    float ob = b2[0];
    if (l15 == 0) {
        #pragma unroll
        for (int mt = 0; mt < 4; ++mt)
            #pragma unroll
            for (int r = 0; r < 4; ++r)
                HF[mt * 16 + kg * 4 + r] = p[mt][r] + ob;
    }
    long pos = wbase + lane;
    if (pos < N) out[nidx[pos]] = HF[lane];
}

// ---------------------------------------------------------------------------
// Fallback: monolithic fused kernel, packed grids, unsorted (~237us, r2)
// ---------------------------------------------------------------------------
__global__ __launch_bounds__(256)
void fused_fallback_kernel(const float* __restrict__ x,
                           const float* __restrict__ scales,
                           const float* __restrict__ trans,
                           const __half2* __restrict__ pg,
                           const float* __restrict__ W0, const float* __restrict__ b0,
                           const float* __restrict__ W1, const float* __restrict__ b1,
                           const float* __restrict__ W2, const float* __restrict__ b2,
                           float* __restrict__ out, int N)
{
    __shared__ float sW0[NPL*NPL], sW1[NPL*NPL], sW2[NPL], sb0[NPL], sb1[NPL];
    __shared__ float sA[NG*3], sB[NG*3];
    const int tid = threadIdx.x;
    for (int i = tid; i < NPL*NPL; i += 256) { sW0[i] = W0[i]; sW1[i] = W1[i]; }
    if (tid < NPL) { sW2[tid] = W2[tid]; sb0[tid] = b0[tid]; sb1[tid] = b1[tid]; }
    if (tid < NG*3) {
        const float k = (1.0f / 1.48f) * 31.5f;
        sA[tid] = scales[tid] * k;
        sB[tid] = trans[tid] * k + 31.5f;
    }
    __syncthreads();
    int n = blockIdx.x * 256 + tid;
    if (n >= N) return;
    float px = x[3*n], py = x[3*n+1], pz = x[3*n+2];
    float feat[2*NG];
    #pragma unroll
    for (int g = 0; g < NG; ++g) {
        float fx = fmaf(px, sA[3*g+0], sB[3*g+0]);
        float fy = fmaf(py, sA[3*g+1], sB[3*g+1]);
        float fz = fmaf(pz, sA[3*g+2], sB[3*g+2]);
        float c0 = 0.f, c1 = 0.f;
        if (fx > -1.f && fx < 64.f && fy > -1.f && fy < 64.f && fz > -1.f && fz < 64.f) {
            float flx = floorf(fx), fly = floorf(fy), flz = floorf(fz);
            int x0 = (int)flx, y0 = (int)fly, z0 = (int)flz;
            float wx = fx-flx, wy = fy-fly, wz = fz-flz;
            float wxa[2], wya[2], wza[2]; int xia[2], yia[2], zia[2];
            wxa[0] = (x0 >= 0  && x0   < DG) ? (1.f-wx) : 0.f;
            wxa[1] = (x0 >= -1 && x0+1 < DG) ? wx : 0.f;
            wya[0] = (y0 >= 0  && y0   < DG) ? (1.f-wy) : 0.f;
            wya[1] = (y0 >= -1 && y0+1 < DG) ? wy : 0.f;
            wza[0] = (z0 >= 0  && z0   < DG) ? (1.f-wz) : 0.f;
            wza[1] = (z0 >= -1 && z0+1 < DG) ? wz : 0.f;
            xia[0] = min(max(x0,0),DG-1); xia[1] = min(max(x0+1,0),DG-1);
            yia[0] = min(max(y0,0),DG-1); yia[1] = min(max(y0+1,0),DG-1);
            zia[0] = min(max(z0,0),DG-1); zia[1] = min(max(z0+1,0),DG-1);
            #pragma unroll
            for (int dz = 0; dz < 2; ++dz)
                #pragma unroll
                for (int dy = 0; dy < 2; ++dy) {
                    int rowoff = (zia[dz] << 12) + (yia[dy] << 6);
                    float wyz = wya[dy] * wza[dz];
                    #pragma unroll
                    for (int dx = 0; dx < 2; ++dx) {
                        float w = wxa[dx] * wyz;
                        float2 vf = __half22float2(pg[(g << 18) + rowoff + xia[dx]]);
                        c0 = fmaf(w, vf.x, c0); c1 = fmaf(w, vf.y, c1);
                    }
                }
        }
        feat[2*g] = c0; feat[2*g+1] = c1;
    }
    float h1[NPL];
    #pragma unroll
    for (int j = 0; j < NPL; j += 2) {
        float a0=0.f,a1=0.f,a2=0.f,a3=0.f;
        const float* r0 = &sW0[j*NPL]; const float* r1 = &sW0[(j+1)*NPL];
        #pragma unroll
        for (int k = 0; k < NPL; k += 2) {
            a0 = fmaf(feat[k],r0[k],a0); a1 = fmaf(feat[k+1],r0[k+1],a1);
            a2 = fmaf(feat[k],r1[k],a2); a3 = fmaf(feat[k+1],r1[k+1],a3);
        }
        h1[j] = fmaxf((a0+a1)+sb0[j],0.f); h1[j+1] = fmaxf((a2+a3)+sb0[j+1],0.f);
    }
    #pragma unroll
    for (int j = 0; j < NPL; j += 2) {
        float a0=0.f,a1=0.f,a2=0.f,a3=0.f;
        const float* r0 = &sW1[j*NPL]; const float* r1 = &sW1[(j+1)*NPL];
        #pragma unroll
        for (int k = 0; k < NPL; k += 2) {
            a0 = fmaf(h1[k],r0[k],a0); a1 = fmaf(h1[k+1],r0[k+1],a1);
            a2 = fmaf(h1[k],r1[k],a2); a3 = fmaf(h1[k+1],r1[k+1],a3);
        }
        feat[j] = fmaxf((a0+a1)+sb1[j],0.f); feat[j+1] = fmaxf((a2+a3)+sb1[j+1],0.f);
    }
    float a0 = 0.f, a1 = 0.f;
    #pragma unroll
    for (int k = 0; k < NPL; k += 2) { a0 = fmaf(feat[k],sW2[k],a0); a1 = fmaf(feat[k+1],sW2[k+1],a1); }
    out[n] = (a0+a1) + b2[0];
}

// ---------------------------------------------------------------------------
extern "C" void kernel_launch(void* const* d_in, const int* in_sizes, int n_in,
                              void* d_out, int out_size, void* d_ws, size_t ws_size,
                              hipStream_t stream) {
    const float* x  = (const float*)d_in[0];
    const float* gs = (const float*)d_in[1];
    const float* gt = (const float*)d_in[2];
    const float* fg = (const float*)d_in[3];
    const float* W0 = (const float*)d_in[4];
    const float* b0 = (const float*)d_in[5];
    const float* W1 = (const float*)d_in[6];
    const float* b1 = (const float*)d_in[7];
    const float* W2 = (const float*)d_in[8];
    const float* b2 = (const float*)d_in[9];
    float* out = (float*)d_out;

    const int N = out_size;

    const size_t pg_bytes   = (size_t)NG * (1 << 18) * 4;                 // 33.5 MB
    const size_t feat_bytes = (size_t)N * 8 * sizeof(int4);               // 67.1 MB
    const size_t sort_bytes = (size_t)N * sizeof(float4);                 // 8 MB
    const size_t nidx_bytes = (size_t)N * sizeof(int);                    // 2 MB
    const size_t cs_bytes   = ((NC2 + 1 + 15) & ~15) * sizeof(int);       // 16.4 KB
    const size_t hist_bytes = (size_t)NC2 * HPAD * sizeof(int);           // 64 KB
    const size_t need_full  = pg_bytes + feat_bytes + sort_bytes + nidx_bytes
                            + cs_bytes + 2 * hist_bytes;

    if (ws_size >= need_full) {
        char* w = (char*)d_ws;
        unsigned* pg        = (unsigned*)w;  w += pg_bytes;
        int4*     featbuf   = (int4*)w;      w += feat_bytes;
        float4*   sorted    = (float4*)w;    w += sort_bytes;
        int*      nidx      = (int*)w;       w += nidx_bytes;
        int*      cellstart = (int*)w;       w += cs_bytes;
        int*      ghist     = (int*)w;       w += hist_bytes;
        int*      gcur      = (int*)w;

        int total4 = NG << 16;
        int nblk   = (N + BS - 1) / BS;
        pack_grids_kernel<<<(total4 + 255) / 256, 256, 0, stream>>>(fg, (uint4*)pg, total4);
        hipMemsetAsync(ghist, 0, hist_bytes, stream);
        hist_kernel<<<nblk, BS, 0, stream>>>(x, N, ghist);
        scan_kernel<<<1, 1024, 0, stream>>>(ghist, gcur, cellstart);
        scatter_kernel<<<nblk, BS, 0, stream>>>(x, N, gcur, sorted, nidx);
        gather_kernel<<<NCELL * 2, BS, 0, stream>>>(
            sorted, cellstart, gs, gt, pg, featbuf, N);
        mlp_kernel<<<(N + MBS - 1) / MBS, MBS, 0, stream>>>(
            featbuf, nidx, W0, b0, W1, b1, W2, b2, out, N);
    } else if (ws_size >= pg_bytes) {
        unsigned* pg = (unsigned*)d_ws;
        int total4 = NG << 16;
        pack_grids_kernel<<<(total4 + 255) / 256, 256, 0, stream>>>(fg, (uint4*)pg, total4);
        fused_fallback_kernel<<<(N + 255) / 256, 256, 0, stream>>>(
            x, gs, gt, (const __half2*)pg, W0, b0, W1, b1, W2, b2, out, N);
    } else {
        fused_fallback_kernel<<<(N + 255) / 256, 256, 0, stream>>>(
            x, gs, gt, (const __half2*)fg, W0, b0, W1, b1, W2, b2, out, N);
    }
}

// Round 8
// 186.415 us; speedup vs baseline: 1.0154x; 1.0154x over previous
//
#include <hip/hip_runtime.h>
#include <hip/hip_fp16.h>

#define NG    32
#define DG    64
#define NPL   64
#define CPD2  16               // sort granularity (fine cells)
#define NC2   4096             // 16^3 sort bins
#define NCELL 512              // gather cells (8^3)
#define HPAD  4                // ints per padded counter (16B)
#define BS    512
#define GBS   1024             // gather block size (one block per cell)
#define TV    4096             // 16^3 voxels per tile
#define HS    68               // mlp sH row stride (f16) — bank-conflict pad

// tile bank swizzle: XOR z-bits (idx[10:8]) into bank bits (idx[4:2]).
// Applied identically on ds_write (staging) and ds_read (sampling).
#define SWZ(i) ((i) ^ (((i) >> 6) & 28))

typedef _Float16 half8 __attribute__((ext_vector_type(8)));
typedef float    floatx4 __attribute__((ext_vector_type(4)));

// ---------------------------------------------------------------------------
// Pack: [G][2][64][64][64] f32 -> [G][64][64][64] half2  (vectorized x4)
// ---------------------------------------------------------------------------
__global__ void pack_grids_kernel(const float* __restrict__ fg,
                                  uint4* __restrict__ pg, int total4) {
    int idx = blockIdx.x * blockDim.x + threadIdx.x;
    if (idx >= total4) return;
    int g  = idx >> 16;
    int v4 = (idx & 65535) << 2;
    const float* base = fg + ((size_t)g << 19);
    float4 a = *(const float4*)(base + v4);
    float4 b = *(const float4*)(base + (1 << 18) + v4);
    uint4 o;
    __half2 h;
    h = __floats2half2_rn(a.x, b.x); o.x = *(unsigned*)&h;
    h = __floats2half2_rn(a.y, b.y); o.y = *(unsigned*)&h;
    h = __floats2half2_rn(a.z, b.z); o.z = *(unsigned*)&h;
    h = __floats2half2_rn(a.w, b.w); o.w = *(unsigned*)&h;
    pg[idx] = o;
}

// ---------------------------------------------------------------------------
// Morton helpers. Fine code (4 bits/dim): low 3 bits = octant within the
// coarse 8^3 cell, so fine codes [c*8, c*8+8) are coarse cell c's children.
// ---------------------------------------------------------------------------
__device__ __forceinline__ int morton16(int cx, int cy, int cz) {
    int m = 0;
    #pragma unroll
    for (int b = 0; b < 4; ++b)
        m |= (((cx >> b) & 1) << (3 * b))
           | (((cy >> b) & 1) << (3 * b + 1))
           | (((cz >> b) & 1) << (3 * b + 2));
    return m;
}
__device__ __forceinline__ int cell_of(float px, float py, float pz) {
    int cx = min(max((int)((px + 1.0f) * (0.5f * CPD2)), 0), CPD2 - 1);
    int cy = min(max((int)((py + 1.0f) * (0.5f * CPD2)), 0), CPD2 - 1);
    int cz = min(max((int)((pz + 1.0f) * (0.5f * CPD2)), 0), CPD2 - 1);
    return morton16(cx, cy, cz);
}

__global__ __launch_bounds__(BS)
void hist_kernel(const float* __restrict__ x, int N, int* __restrict__ ghist) {
    __shared__ int lh[NC2];
    for (int i = threadIdx.x; i < NC2; i += BS) lh[i] = 0;
    __syncthreads();
    int n = blockIdx.x * BS + threadIdx.x;
    if (n < N) atomicAdd(&lh[cell_of(x[3*n], x[3*n+1], x[3*n+2])], 1);
    __syncthreads();
    for (int i = threadIdx.x; i < NC2; i += BS) {
        int c = lh[i];
        if (c) atomicAdd(&ghist[i * HPAD], c);
    }
}

__global__ __launch_bounds__(1024)
void scan_kernel(const int* __restrict__ ghist, int* __restrict__ gcursor,
                 int* __restrict__ cellstart) {
    __shared__ int tsum[1024];
    int t = threadIdx.x;
    int v0 = ghist[(t * 4 + 0) * HPAD];
    int v1 = ghist[(t * 4 + 1) * HPAD];
    int v2 = ghist[(t * 4 + 2) * HPAD];
    int v3 = ghist[(t * 4 + 3) * HPAD];
    tsum[t] = v0 + v1 + v2 + v3;
    __syncthreads();
    #pragma unroll
    for (int off = 1; off < 1024; off <<= 1) {
        int u = (t >= off) ? tsum[t - off] : 0;
        __syncthreads();
        tsum[t] += u;
        __syncthreads();
    }
    int base = (t == 0) ? 0 : tsum[t - 1];
    gcursor[(t*4+0)*HPAD] = base; cellstart[t*4+0] = base; base += v0;
    gcursor[(t*4+1)*HPAD] = base; cellstart[t*4+1] = base; base += v1;
    gcursor[(t*4+2)*HPAD] = base; cellstart[t*4+2] = base; base += v2;
    gcursor[(t*4+3)*HPAD] = base; cellstart[t*4+3] = base;
    if (t == 1023) cellstart[NC2] = tsum[1023];
}

__global__ __launch_bounds__(BS)
void scatter_kernel(const float* __restrict__ x, int N,
                    int* __restrict__ gcursor, float4* __restrict__ sorted,
                    int* __restrict__ nidx) {
    __shared__ int cnt[NC2];
    __shared__ int base[NC2];
    int tid = threadIdx.x;
    for (int i = tid; i < NC2; i += BS) cnt[i] = 0;
    __syncthreads();
    int n = blockIdx.x * BS + tid;
    float px = 0.f, py = 0.f, pz = 0.f;
    int c = 0, r = 0;
    bool act = (n < N);
    if (act) {
        px = x[3*n]; py = x[3*n+1]; pz = x[3*n+2];
        c = cell_of(px, py, pz);
        r = atomicAdd(&cnt[c], 1);
    }
    __syncthreads();
    for (int i = tid; i < NC2; i += BS) {
        int cc = cnt[i];
        base[i] = cc ? atomicAdd(&gcursor[i * HPAD], cc) : 0;
    }
    __syncthreads();
    if (act) {
        int pos = base[c] + r;
        sorted[pos] = make_float4(px, py, pz, 0.0f);
        nidx[pos]   = n;
    }
}

// ---------------------------------------------------------------------------
__device__ __forceinline__ float2 h2_to_f2(unsigned u) {
    __half2 h = *reinterpret_cast<__half2*>(&u);
    return __half22float2(h);
}

// FAST: whole cell strictly interior AND index-safe (fmn>=0, fmx<=62.9):
// no boundary weight masks, no index clamps (window provably covers corners).
template<bool FAST>
__device__ __forceinline__ unsigned sample_tile(
    const unsigned* __restrict__ tl,
    float px, float py, float pz,
    float A0, float A1, float A2, float B0, float B1, float B2,
    int ox, int oy, int oz)
{
    float fx = fmaf(px, A0, B0);
    float fy = fmaf(py, A1, B1);
    float fz = fmaf(pz, A2, B2);
    float flx = floorf(fx), fly = floorf(fy), flz = floorf(fz);
    int x0 = (int)flx, y0 = (int)fly, z0 = (int)flz;
    float wx = fx - flx, wy = fy - fly, wz = fz - flz;

    float wxa0, wxa1, wya0, wya1, wza0, wza1;
    int ix0, ix1, iy0, iy1, iz0, iz1;
    if (FAST) {
        wxa0 = 1.0f - wx; wxa1 = wx;
        wya0 = 1.0f - wy; wya1 = wy;
        wza0 = 1.0f - wz; wza1 = wz;
        ix0 = x0 - ox;            ix1 = ix0 + 1;
        iy0 = (y0 - oy) << 4;     iy1 = iy0 + 16;
        iz0 = (z0 - oz) << 8;     iz1 = iz0 + 256;
    } else {
        wxa0 = (x0 >= 0  && x0     < DG) ? (1.0f - wx) : 0.0f;
        wxa1 = (x0 >= -1 && x0 + 1 < DG) ? wx          : 0.0f;
        wya0 = (y0 >= 0  && y0     < DG) ? (1.0f - wy) : 0.0f;
        wya1 = (y0 >= -1 && y0 + 1 < DG) ? wy          : 0.0f;
        wza0 = (z0 >= 0  && z0     < DG) ? (1.0f - wz) : 0.0f;
        wza1 = (z0 >= -1 && z0 + 1 < DG) ? wz          : 0.0f;
        ix0 = min(max(x0     - ox, 0), 15);
        ix1 = min(max(x0 + 1 - ox, 0), 15);
        iy0 = (min(max(y0     - oy, 0), 15)) << 4;
        iy1 = (min(max(y0 + 1 - oy, 0), 15)) << 4;
        iz0 = (min(max(z0     - oz, 0), 15)) << 8;
        iz1 = (min(max(z0 + 1 - oz, 0), 15)) << 8;
    }
    const int m0 = (iz0 >> 6) & 28;     // swizzle masks (z-dependent)
    const int m1 = (iz1 >> 6) & 28;

    float w00 = wya0 * wza0, w10 = wya1 * wza0;
    float w01 = wya0 * wza1, w11 = wya1 * wza1;

    float c0 = 0.0f, c1 = 0.0f;
    float2 v;
    v = h2_to_f2(tl[(iz0+iy0+ix0)^m0]); c0 = fmaf(wxa0*w00, v.x, c0); c1 = fmaf(wxa0*w00, v.y, c1);
    v = h2_to_f2(tl[(iz0+iy0+ix1)^m0]); c0 = fmaf(wxa1*w00, v.x, c0); c1 = fmaf(wxa1*w00, v.y, c1);
    v = h2_to_f2(tl[(iz0+iy1+ix0)^m0]); c0 = fmaf(wxa0*w10, v.x, c0); c1 = fmaf(wxa0*w10, v.y, c1);
    v = h2_to_f2(tl[(iz0+iy1+ix1)^m0]); c0 = fmaf(wxa1*w10, v.x, c0); c1 = fmaf(wxa1*w10, v.y, c1);
    v = h2_to_f2(tl[(iz1+iy0+ix0)^m1]); c0 = fmaf(wxa0*w01, v.x, c0); c1 = fmaf(wxa0*w01, v.y, c1);
    v = h2_to_f2(tl[(iz1+iy0+ix1)^m1]); c0 = fmaf(wxa1*w01, v.x, c0); c1 = fmaf(wxa1*w01, v.y, c1);
    v = h2_to_f2(tl[(iz1+iy1+ix0)^m1]); c0 = fmaf(wxa0*w11, v.x, c0); c1 = fmaf(wxa0*w11, v.y, c1);
    v = h2_to_f2(tl[(iz1+iy1+ix1)^m1]); c0 = fmaf(wxa1*w11, v.x, c0); c1 = fmaf(wxa1*w11, v.y, c1);

    __half2 hv = __floats2half2_rn(c0, c1);
    return *reinterpret_cast<unsigned*>(&hv);
}

// ---------------------------------------------------------------------------
// Gather: ONE 1024-thread block per 8^3 cell (512 blocks = 2/CU, 32 waves/CU).
// Tiles staged once per cell. Per-(cell,grid) classification: skip/fast/slow.
// ---------------------------------------------------------------------------
__global__ __launch_bounds__(GBS)
void gather_kernel(const float4* __restrict__ sorted,
                   const int*   __restrict__ cs16,
                   const float* __restrict__ scales,
                   const float* __restrict__ trans,
                   const unsigned* __restrict__ pg,
                   int4* __restrict__ featbuf, int N)
{
    __shared__ float    sA[NG * 3];
    __shared__ float    sB[NG * 3];
    __shared__ int      sO[NG * 3];
    __shared__ int      sCls[NG];
    __shared__ int      sList[NG + 1];
    __shared__ unsigned tile[2][TV];      // 32 KB

    const int tid  = threadIdx.x;
    const int cell = blockIdx.x;
    const int c    = ((cell & 7) << 6) + (cell >> 3);   // XCD-chunked swizzle

    int s0c = cs16[c * 8];
    int ec  = cs16[c * 8 + 8];
    if (s0c >= ec) return;               // uniform exit before any barrier

    int cx = (c & 1)        | (((c >> 3) & 1) << 1) | (((c >> 6) & 1) << 2);
    int cy = ((c >> 1) & 1) | (((c >> 4) & 1) << 1) | (((c >> 7) & 1) << 2);
    int cz = ((c >> 2) & 1) | (((c >> 5) & 1) << 1) | (((c >> 8) & 1) << 2);

    if (tid < NG * 3) {
        const float k = (1.0f / 1.48f) * 31.5f;
        float A  = scales[tid] * k;
        float Bv = trans[tid] * k + 31.5f;
        sA[tid] = A; sB[tid] = Bv;
        int d  = tid % 3;
        int cc = (d == 0) ? cx : ((d == 1) ? cy : cz);
        int o  = (int)floorf(fmaf((float)cc * 0.25f - 1.0f, A, Bv));
        sO[tid] = min(max(o, 0), 48);
    }
    __syncthreads();
    if (tid < NG) {
        bool skip = false, fast = true;
        #pragma unroll
        for (int d = 0; d < 3; ++d) {
            float A = sA[3 * tid + d], B = sB[3 * tid + d];
            int  cc = (d == 0) ? cx : ((d == 1) ? cy : cz);
            float lo = fmaf((float)cc, 0.25f, -1.0f) - 1e-4f;
            float hi = lo + 0.25f + 2e-4f;
            float fmn = fmaf(lo, A, B);   // A > 0 always (scales > 0)
            float fmx = fmaf(hi, A, B);
            skip = skip || (fmx <= -1.0f) || (fmn >= 64.0f);
            fast = fast && (fmn >= 0.0f) && (fmx <= 62.9f);
        }
        sCls[tid] = skip ? 0 : (fast ? 1 : 2);
    }
    __syncthreads();
    if (tid == 0) {
        int n2 = 0;
        for (int g = 0; g < NG; ++g)
            if (sCls[g]) sList[n2++] = g;
        sList[NG] = n2;
    }
    __syncthreads();
    const int nAct = sList[NG];

    // points: 1/thread steady-state; slot 1 only for cells with >1024 pts
    int  ip0 = s0c + tid,        ip1 = s0c + GBS + tid;
    bool act0 = (ip0 < ec),      act1 = (ip1 < ec);
    float px0 = 0.f, py0 = 0.f, pz0 = 0.f;
    float px1 = 0.f, py1 = 0.f, pz1 = 0.f;
    if (act0) { float4 q = sorted[ip0]; px0 = q.x; py0 = q.y; pz0 = q.z; }
    if (act1) { float4 q = sorted[ip1]; px1 = q.x; py1 = q.y; pz1 = q.z; }

    // prologue: stage first active grid into buf 0 (4 voxels/thread)
    if (nAct > 0) {
        int g0 = sList[0];
        int ox = sO[3*g0], oy = sO[3*g0+1], oz = sO[3*g0+2];
        const unsigned* gb = pg + ((size_t)g0 << 18);
        #pragma unroll
        for (int jj = 0; jj < 4; ++jj) {
            int v = tid + (jj << 10);
            tile[0][SWZ(v)] = gb[((oz + (v >> 8)) << 12) + ((oy + ((v >> 4) & 15)) << 6)
                                 + ox + (v & 15)];
        }
    }
    __syncthreads();

    unsigned fp0[4], fp1[4];
    unsigned r[4];
    int j = 0;

    #pragma unroll 1
    for (int w = 0; w < 8; ++w) {
        #pragma unroll
        for (int q = 0; q < 4; ++q) {
            int g   = 4 * w + q;
            int cls = sCls[g];                 // block-uniform
            if (cls == 0) { fp0[q] = 0u; fp1[q] = 0u; continue; }

            const unsigned* tl = &tile[j & 1][0];
            bool more = (j + 1 < nAct);
            if (more) {                        // issue next tile's loads
                int gn = sList[j + 1];
                int ox = sO[3*gn], oy = sO[3*gn+1], oz = sO[3*gn+2];
                const unsigned* gb = pg + ((size_t)gn << 18);
                #pragma unroll
                for (int jj = 0; jj < 4; ++jj) {
                    int v = tid + (jj << 10);
                    r[jj] = gb[((oz + (v >> 8)) << 12) + ((oy + ((v >> 4) & 15)) << 6)
                               + ox + (v & 15)];
                }
            }

            float A0 = sA[3*g], A1 = sA[3*g+1], A2 = sA[3*g+2];
            float B0 = sB[3*g], B1 = sB[3*g+1], B2 = sB[3*g+2];
            int   ox = sO[3*g], oy = sO[3*g+1], oz = sO[3*g+2];
            fp1[q] = 0u;
            if (cls == 1) {
                fp0[q] = act0 ? sample_tile<true >(tl, px0,py0,pz0, A0,A1,A2,B0,B1,B2, ox,oy,oz) : 0u;
                if (act1)
                    fp1[q] = sample_tile<true >(tl, px1,py1,pz1, A0,A1,A2,B0,B1,B2, ox,oy,oz);
            } else {
                fp0[q] = act0 ? sample_tile<false>(tl, px0,py0,pz0, A0,A1,A2,B0,B1,B2, ox,oy,oz) : 0u;
                if (act1)
                    fp1[q] = sample_tile<false>(tl, px1,py1,pz1, A0,A1,A2,B0,B1,B2, ox,oy,oz);
            }

            if (more) {                        // land staged regs into other buf
                unsigned* td = &tile[(j & 1) ^ 1][0];
                #pragma unroll
                for (int jj = 0; jj < 4; ++jj) {
                    int v = tid + (jj << 10);
                    td[SWZ(v)] = r[jj];
                }
            }
            __syncthreads();
            ++j;
        }
        const size_t plane = (size_t)w * (size_t)N;
        if (act0) featbuf[plane + ip0] =
            make_int4((int)fp0[0], (int)fp0[1], (int)fp0[2], (int)fp0[3]);
        if (act1) featbuf[plane + ip1] =
            make_int4((int)fp1[0], (int)fp1[1], (int)fp1[2], (int)fp1[3]);
    }
}

// ---------------------------------------------------------------------------
// MFMA MLP: wave = 64 points; A from featbuf planes, B = W rows (f16, LDS).
// sH row stride padded to 68 f16 to break ds_read_b128 bank aliasing.
// ---------------------------------------------------------------------------
#define MBS 256
__global__ __launch_bounds__(MBS)
void mlp_kernel(const int4* __restrict__ featbuf,
                const int* __restrict__ nidx,
                const float* __restrict__ W0, const float* __restrict__ b0,
                const float* __restrict__ W1, const float* __restrict__ b1,
                const float* __restrict__ W2, const float* __restrict__ b2,
                float* __restrict__ out, int N)
{
    __shared__ __align__(16) _Float16 sW0h[NPL * NPL];
    __shared__ __align__(16) _Float16 sW1h[NPL * NPL];
    __shared__ float sb0f[NPL], sb1f[NPL], sW2f[NPL];
    __shared__ __align__(16) _Float16 sH[4][NPL * HS];

    int tid = threadIdx.x;
    for (int i = tid; i < NPL * NPL; i += MBS) {
        sW0h[i] = (_Float16)W0[i];
        sW1h[i] = (_Float16)W1[i];
    }
    if (tid < NPL) { sb0f[tid] = b0[tid]; sb1f[tid] = b1[tid]; sW2f[tid] = W2[tid]; }
    __syncthreads();

    const int wave = tid >> 6;
    const int lane = tid & 63;
    const int l15  = lane & 15;
    const int kg   = lane >> 4;
    const long wbase = (long)blockIdx.x * MBS + wave * 64;
    if (wbase >= N) return;

    half8 B0[4][2], B1[4][2];
    float bias0[4], bias1[4], w2v[4];
    #pragma unroll
    for (int nt = 0; nt < 4; ++nt) {
        int ch = nt * 16 + l15;
        #pragma unroll
        for (int kh = 0; kh < 2; ++kh) {
            int k = kh * 32 + kg * 8;
            B0[nt][kh] = *(const half8*)&sW0h[ch * NPL + k];
            B1[nt][kh] = *(const half8*)&sW1h[ch * NPL + k];
        }
        bias0[nt] = sb0f[ch];
        bias1[nt] = sb1f[ch];
        w2v[nt]   = sW2f[ch];
    }

    _Float16* H = &sH[wave][0];

    // ---- layer 0 ----
    floatx4 acc[4][4];
    #pragma unroll
    for (int mt = 0; mt < 4; ++mt) {
        long pt = wbase + mt * 16 + l15;
        if (pt > N - 1) pt = N - 1;
        int4 t0 = featbuf[(size_t)kg * N + pt];
        int4 t1 = featbuf[(size_t)(4 + kg) * N + pt];
        half8 a0 = *reinterpret_cast<half8*>(&t0);
        half8 a1 = *reinterpret_cast<half8*>(&t1);
        #pragma unroll
        for (int nt = 0; nt < 4; ++nt) {
            floatx4 cc = {0.f, 0.f, 0.f, 0.f};
            cc = __builtin_amdgcn_mfma_f32_16x16x32_f16(a0, B0[nt][0], cc, 0, 0, 0);
            cc = __builtin_amdgcn_mfma_f32_16x16x32_f16(a1, B0[nt][1], cc, 0, 0, 0);
            acc[mt][nt] = cc;
        }
    }
    #pragma unroll
    for (int mt = 0; mt < 4; ++mt)
        #pragma unroll
        for (int nt = 0; nt < 4; ++nt) {
            int ch = nt * 16 + l15;
            #pragma unroll
            for (int r = 0; r < 4; ++r) {
                float v = fmaxf(acc[mt][nt][r] + bias0[nt], 0.0f);
                H[(mt * 16 + kg * 4 + r) * HS + ch] = (_Float16)v;
            }
        }

    // ---- layer 1 ----
    floatx4 acc2[4][4];
    #pragma unroll
    for (int mt = 0; mt < 4; ++mt) {
        const _Float16* hp = &H[(mt * 16 + l15) * HS];
        half8 a0 = *(const half8*)&hp[kg * 8];
        half8 a1 = *(const half8*)&hp[32 + kg * 8];
        #pragma unroll
        for (int nt = 0; nt < 4; ++nt) {
            floatx4 cc = {0.f, 0.f, 0.f, 0.f};
            cc = __builtin_amdgcn_mfma_f32_16x16x32_f16(a0, B1[nt][0], cc, 0, 0, 0);
            cc = __builtin_amdgcn_mfma_f32_16x16x32_f16(a1, B1[nt][1], cc, 0, 0, 0);
            acc2[mt][nt] = cc;
        }
    }

    // ---- layer 2 + 16-lane reduce ----
    float p[4][4];
    #pragma unroll
    for (int mt = 0; mt < 4; ++mt)
        #pragma unroll
        for (int r = 0; r < 4; ++r) p[mt][r] = 0.0f;
    #pragma unroll
    for (int mt = 0; mt < 4; ++mt)
        #pragma unroll
        for (int nt = 0; nt < 4; ++nt)
            #pragma unroll
            for (int r = 0; r < 4; ++r) {
                float v = fmaxf(acc2[mt][nt][r] + bias1[nt], 0.0f);
                p[mt][r] = fmaf(v, w2v[nt], p[mt][r]);
            }
    #pragma unroll
    for (int mt = 0; mt < 4; ++mt)
        #pragma unroll
        for (int r = 0; r < 4; ++r) {
            float s = p[mt][r];
            s += __shfl_xor(s, 1);
            s += __shfl_xor(s, 2);
            s += __shfl_xor(s, 4);
            s += __shfl_xor(s, 8);
            p[mt][r] = s;
        }

    float* HF = (float*)H;
    float ob = b2[0];
    if (l15 == 0) {
        #pragma unroll
        for (int mt = 0; mt < 4; ++mt)
            #pragma unroll
            for (int r = 0; r < 4; ++r)
                HF[mt * 16 + kg * 4 + r] = p[mt][r] + ob;
    }
    long pos = wbase + lane;
    if (pos < N) out[nidx[pos]] = HF[lane];
}

// ---------------------------------------------------------------------------
// Fallback: monolithic fused kernel, packed grids, unsorted (~237us, r2)
// ---------------------------------------------------------------------------
__global__ __launch_bounds__(256)
void fused_fallback_kernel(const float* __restrict__ x,
                           const float* __restrict__ scales,
                           const float* __restrict__ trans,
                           const __half2* __restrict__ pg,
                           const float* __restrict__ W0, const float* __restrict__ b0,
                           const float* __restrict__ W1, const float* __restrict__ b1,
                           const float* __restrict__ W2, const float* __restrict__ b2,
                           float* __restrict__ out, int N)
{
    __shared__ float sW0[NPL*NPL], sW1[NPL*NPL], sW2[NPL], sb0[NPL], sb1[NPL];
    __shared__ float sA[NG*3], sB[NG*3];
    const int tid = threadIdx.x;
    for (int i = tid; i < NPL*NPL; i += 256) { sW0[i] = W0[i]; sW1[i] = W1[i]; }
    if (tid < NPL) { sW2[tid] = W2[tid]; sb0[tid] = b0[tid]; sb1[tid] = b1[tid]; }
    if (tid < NG*3) {
        const float k = (1.0f / 1.48f) * 31.5f;
        sA[tid] = scales[tid] * k;
        sB[tid] = trans[tid] * k + 31.5f;
    }
    __syncthreads();
    int n = blockIdx.x * 256 + tid;
    if (n >= N) return;
    float px = x[3*n], py = x[3*n+1], pz = x[3*n+2];
    float feat[2*NG];
    #pragma unroll
    for (int g = 0; g < NG; ++g) {
        float fx = fmaf(px, sA[3*g+0], sB[3*g+0]);
        float fy = fmaf(py, sA[3*g+1], sB[3*g+1]);
        float fz = fmaf(pz, sA[3*g+2], sB[3*g+2]);
        float c0 = 0.f, c1 = 0.f;
        if (fx > -1.f && fx < 64.f && fy > -1.f && fy < 64.f && fz > -1.f && fz < 64.f) {
            float flx = floorf(fx), fly = floorf(fy), flz = floorf(fz);
            int x0 = (int)flx, y0 = (int)fly, z0 = (int)flz;
            float wx = fx-flx, wy = fy-fly, wz = fz-flz;
            float wxa[2], wya[2], wza[2]; int xia[2], yia[2], zia[2];
            wxa[0] = (x0 >= 0  && x0   < DG) ? (1.f-wx) : 0.f;
            wxa[1] = (x0 >= -1 && x0+1 < DG) ? wx : 0.f;
            wya[0] = (y0 >= 0  && y0   < DG) ? (1.f-wy) : 0.f;
            wya[1] = (y0 >= -1 && y0+1 < DG) ? wy : 0.f;
            wza[0] = (z0 >= 0  && z0   < DG) ? (1.f-wz) : 0.f;
            wza[1] = (z0 >= -1 && z0+1 < DG) ? wz : 0.f;
            xia[0] = min(max(x0,0),DG-1); xia[1] = min(max(x0+1,0),DG-1);
            yia[0] = min(max(y0,0),DG-1); yia[1] = min(max(y0+1,0),DG-1);
            zia[0] = min(max(z0,0),DG-1); zia[1] = min(max(z0+1,0),DG-1);
            #pragma unroll
            for (int dz = 0; dz < 2; ++dz)
                #pragma unroll
                for (int dy = 0; dy < 2; ++dy) {
                    int rowoff = (zia[dz] << 12) + (yia[dy] << 6);
                    float wyz = wya[dy] * wza[dz];
                    #pragma unroll
                    for (int dx = 0; dx < 2; ++dx) {
                        float w = wxa[dx] * wyz;
                        float2 vf = __half22float2(pg[(g << 18) + rowoff + xia[dx]]);
                        c0 = fmaf(w, vf.x, c0); c1 = fmaf(w, vf.y, c1);
                    }
                }
        }
        feat[2*g] = c0; feat[2*g+1] = c1;
    }
    float h1[NPL];
    #pragma unroll
    for (int j = 0; j < NPL; j += 2) {
        float a0=0.f,a1=0.f,a2=0.f,a3=0.f;
        const float* r0 = &sW0[j*NPL]; const float* r1 = &sW0[(j+1)*NPL];
        #pragma unroll
        for (int k = 0; k < NPL; k += 2) {
            a0 = fmaf(feat[k],r0[k],a0); a1 = fmaf(feat[k+1],r0[k+1],a1);
            a2 = fmaf(feat[k],r1[k],a2); a3 = fmaf(feat[k+1],r1[k+1],a3);
        }
        h1[j] = fmaxf((a0+a1)+sb0[j],0.f); h1[j+1] = fmaxf((a2+a3)+sb0[j+1],0.f);
    }
    #pragma unroll
    for (int j = 0; j < NPL; j += 2) {
        float a0=0.f,a1=0.f,a2=0.f,a3=0.f;
        const float* r0 = &sW1[j*NPL]; const float* r1 = &sW1[(j+1)*NPL];
        #pragma unroll
        for (int k = 0; k < NPL; k += 2) {
            a0 = fmaf(h1[k],r0[k],a0); a1 = fmaf(h1[k+1],r0[k+1],a1);
            a2 = fmaf(h1[k],r1[k],a2); a3 = fmaf(h1[k+1],r1[k+1],a3);
        }
        feat[j] = fmaxf((a0+a1)+sb1[j],0.f); feat[j+1] = fmaxf((a2+a3)+sb1[j+1],0.f);
    }
    float a0 = 0.f, a1 = 0.f;
    #pragma unroll
    for (int k = 0; k < NPL; k += 2) { a0 = fmaf(feat[k],sW2[k],a0); a1 = fmaf(feat[k+1],sW2[k+1],a1); }
    out[n] = (a0+a1) + b2[0];
}

// ---------------------------------------------------------------------------
extern "C" void kernel_launch(void* const* d_in, const int* in_sizes, int n_in,
                              void* d_out, int out_size, void* d_ws, size_t ws_size,
                              hipStream_t stream) {
    const float* x  = (const float*)d_in[0];
    const float* gs = (const float*)d_in[1];
    const float* gt = (const float*)d_in[2];
    const float* fg = (const float*)d_in[3];
    const float* W0 = (const float*)d_in[4];
    const float* b0 = (const float*)d_in[5];
    const float* W1 = (const float*)d_in[6];
    const float* b1 = (const float*)d_in[7];
    const float* W2 = (const float*)d_in[8];
    const float* b2 = (const float*)d_in[9];
    float* out = (float*)d_out;

    const int N = out_size;

    const size_t pg_bytes   = (size_t)NG * (1 << 18) * 4;                 // 33.5 MB
    const size_t feat_bytes = (size_t)N * 8 * sizeof(int4);               // 67.1 MB
    const size_t sort_bytes = (size_t)N * sizeof(float4);                 // 8 MB
    const size_t nidx_bytes = (size_t)N * sizeof(int);                    // 2 MB
    const size_t cs_bytes   = ((NC2 + 1 + 15) & ~15) * sizeof(int);       // 16.4 KB
    const size_t hist_bytes = (size_t)NC2 * HPAD * sizeof(int);           // 64 KB
    const size_t need_full  = pg_bytes + feat_bytes + sort_bytes + nidx_bytes
                            + cs_bytes + 2 * hist_bytes;

    if (ws_size >= need_full) {
        char* w = (char*)d_ws;
        unsigned* pg        = (unsigned*)w;  w += pg_bytes;
        int4*     featbuf   = (int4*)w;      w += feat_bytes;
        float4*   sorted    = (float4*)w;    w += sort_bytes;
        int*      nidx      = (int*)w;       w += nidx_bytes;
        int*      cellstart = (int*)w;       w += cs_bytes;
        int*      ghist     = (int*)w;       w += hist_bytes;
        int*      gcur      = (int*)w;

        int total4 = NG << 16;
        int nblk   = (N + BS - 1) / BS;
        pack_grids_kernel<<<(total4 + 255) / 256, 256, 0, stream>>>(fg, (uint4*)pg, total4);
        hipMemsetAsync(ghist, 0, hist_bytes, stream);
        hist_kernel<<<nblk, BS, 0, stream>>>(x, N, ghist);
        scan_kernel<<<1, 1024, 0, stream>>>(ghist, gcur, cellstart);
        scatter_kernel<<<nblk, BS, 0, stream>>>(x, N, gcur, sorted, nidx);
        gather_kernel<<<NCELL, GBS, 0, stream>>>(
            sorted, cellstart, gs, gt, pg, featbuf, N);
        mlp_kernel<<<(N + MBS - 1) / MBS, MBS, 0, stream>>>(
            featbuf, nidx, W0, b0, W1, b1, W2, b2, out, N);
    } else if (ws_size >= pg_bytes) {
        unsigned* pg = (unsigned*)d_ws;
        int total4 = NG << 16;
        pack_grids_kernel<<<(total4 + 255) / 256, 256, 0, stream>>>(fg, (uint4*)pg, total4);
        fused_fallback_kernel<<<(N + 255) / 256, 256, 0, stream>>>(
            x, gs, gt, (const __half2*)pg, W0, b0, W1, b1, W2, b2, out, N);
    } else {
        fused_fallback_kernel<<<(N + 255) / 256, 256, 0, stream>>>(
            x, gs, gt, (const __half2*)fg, W0, b0, W1, b1, W2, b2, out, N);
    }
}